// Round 11
// baseline (73500.647 us; speedup 1.0000x reference)
//
#include <hip/hip_runtime.h>

#define TB 1024

// ---- dims: B=64, N=32, H=128, NH=8, HD=16, FF=2048, L=2, NG=1 ----
// per-slot float offsets in ws
static constexpr int S_XEMB=0, S_PE=4096, S_MEM=8320, S_KC=12416, S_RG=28800,
  S_RA=32896, S_TGT=36992, S_X=41216, S_Y=45440, S_K=49664, S_V=53888,
  S_ATT=58112, S_LNT=62336, S_HID=66560, S_QG=134144, S_VA=134272, S_VB=134400,
  S_LOG=134528, S_SOFT=134561, S_LP=134594, S_MASK=134627, S_MROW=134659,
  S_LL=134739, S_POS=134740, PB=134784;

struct Params {
  const float *x, *fc_w, *fc_b, *bos, *demb_w, *demb_b;
  const float *eqkv_w, *eqkv_b, *eout_w, *eout_b, *eff1_w, *eff1_b, *eff2_w, *eff2_b;
  const float *eln1g, *eln1b, *eln2g, *eln2b;
  const float *dsaqkv_w, *dsaqkv_b, *dsaout_w, *dsaout_b;
  const float *dcaqkv_w, *dcaqkv_b, *dcaout_w, *dcaout_b;
  const float *dff1_w, *dff1_b, *dff2_w, *dff2_b;
  const float *dln1g, *dln1b, *dln2g, *dln2b, *dln3g, *dln3b;
  const float *wref_g, *wq_g, *v_g, *wref_a, *wq_a, *v_a;
  float* ws; float* out; int nb;
};

// ---- numpy-faithful scalar ops (unfused, uncontracted) ----
__device__ __forceinline__ float fadd(float a, float b){ return __fadd_rn(a, b); }
__device__ __forceinline__ float fmul(float a, float b){ return __fmul_rn(a, b); }
__device__ __forceinline__ float fsub(float a, float b){ return __fsub_rn(a, b); }
__device__ __forceinline__ float fdiv(float a, float b){ return __fdiv_rn(a, b); }
__device__ __forceinline__ float exp_np(float x){ return (float)exp((double)x); }
__device__ __forceinline__ float tanh_np(float x){ return (float)tanh((double)x); }
__device__ __forceinline__ float log_np(float x){ return (float)log((double)x); }
__device__ __forceinline__ float sin_np(float x){ return (float)sin((double)x); }
__device__ __forceinline__ float cos_np(float x){ return (float)cos((double)x); }
__device__ __forceinline__ float sqrt_np(float x){ return (float)sqrt((double)x); }

// numpy pairwise_sum for n<=128: 8-accumulator unrolled + tree + remainder
__device__ float np_sum(const float* x, int n){
  if (n < 8){
    float s = 0.f;
    for (int k = 0; k < n; k++) s = fadd(s, x[k]);
    return s;
  }
  float r0=x[0],r1=x[1],r2=x[2],r3=x[3],r4=x[4],r5=x[5],r6=x[6],r7=x[7];
  int nb = n & ~7;
  for (int k = 8; k < nb; k += 8){
    r0=fadd(r0,x[k]);   r1=fadd(r1,x[k+1]); r2=fadd(r2,x[k+2]); r3=fadd(r3,x[k+3]);
    r4=fadd(r4,x[k+4]); r5=fadd(r5,x[k+5]); r6=fadd(r6,x[k+6]); r7=fadd(r7,x[k+7]);
  }
  float res = fadd(fadd(fadd(r0,r1), fadd(r2,r3)), fadd(fadd(r4,r5), fadd(r6,r7)));
  for (int k = nb; k < n; k++) res = fadd(res, x[k]);
  return res;
}

// BLAS sgemm-equivalent dot: sequential fmaf chain over 128, bias added after
template<bool RELU, bool BIAS>
__device__ void gemv(float* __restrict__ out, const float* __restrict__ xin,
                     const float* __restrict__ W, const float* __restrict__ bias,
                     int OUTW, int P, int tid){
  for (int idx = tid; idx < P*OUTW; idx += TB){
    int p = idx / OUTW, o = idx - p*OUTW;
    const float* xr = xin + (p<<7);
    const float* wr = W + o*128;
    float a = 0.f;
    for (int c = 0; c < 128; c++) a = fmaf(xr[c], wr[c], a);
    if (BIAS) a = fadd(a, bias[o]);
    if (RELU) a = fmaxf(a, 0.f);
    out[idx] = a;
  }
}

// qkv projection -> split q/k/v (each row stride 128)
__device__ void qkv(float* __restrict__ q, float* __restrict__ k, float* __restrict__ v,
                    const float* __restrict__ xin, const float* __restrict__ W,
                    const float* __restrict__ b, int P, int tid){
  for (int idx = tid; idx < P*384; idx += TB){
    int p = idx / 384, o = idx - p*384;
    const float* xr = xin + (p<<7);
    const float* wr = W + o*128;
    float a = 0.f;
    for (int c = 0; c < 128; c++) a = fmaf(xr[c], wr[c], a);
    a = fadd(a, b[o]);
    if (o < 128)      q[(p<<7) + o] = a;
    else if (o < 256) k[(p<<7) + o - 128] = a;
    else              v[(p<<7) + o - 256] = a;
  }
}

// MHA, numpy-einsum semantics:
//  QK dot over d=16: SSE2 path — 4-lane acc, unfused mul/add, hsum (a0+a2)+(a1+a3)
//  softmax: exp(x-max) (double->f32), denominator = np_sum over SLOTS, div
//  PV: strided einsum — scalar sequential unfused over valid keys
__device__ void attn(float* __restrict__ out, const float* __restrict__ Qb,
                     const float* __restrict__ Kb, const float* __restrict__ Vb,
                     int nq, int nv, int SLOTS, int tid){
  for (int t = tid; t < 8*nq; t += TB){
    int h = t / nq, p = t - h*nq;
    const float* qv = Qb + (p<<7) + h*16;
    float sc[33];
    float m = -3.0e38f;
    for (int k = 0; k < nv; k++){
      const float* kv = Kb + (k<<7) + h*16;
      float a0=0.f, a1=0.f, a2=0.f, a3=0.f;
      #pragma unroll
      for (int j = 0; j < 4; j++){
        a0 = fadd(a0, fmul(qv[4*j],   kv[4*j]));
        a1 = fadd(a1, fmul(qv[4*j+1], kv[4*j+1]));
        a2 = fadd(a2, fmul(qv[4*j+2], kv[4*j+2]));
        a3 = fadd(a3, fmul(qv[4*j+3], kv[4*j+3]));
      }
      float s = fadd(fadd(a0, a2), fadd(a1, a3));
      s = fdiv(s, 4.0f);
      sc[k] = s;
      m = fmaxf(m, s);
    }
    for (int k = 0; k < nv; k++) sc[k] = exp_np(fsub(sc[k], m));
    for (int k = nv; k < SLOTS; k++) sc[k] = 0.f;
    float es = np_sum(sc, SLOTS);
    for (int k = 0; k < nv; k++) sc[k] = fdiv(sc[k], es);
    for (int d = 0; d < 16; d++){
      float a = 0.f;
      for (int k = 0; k < nv; k++) a = fadd(a, fmul(sc[k], Vb[(k<<7) + h*16 + d]));
      out[(p<<7) + h*16 + d] = a;
    }
  }
}

// LN over prepared LNT rows -> out. numpy: mean=np_sum/128 (div), two-pass var,
// ((x-m)/sqrt(v+eps))*g + b with separate roundings.
__device__ void ln_run(float* __restrict__ F, float* __restrict__ out,
                       const float* __restrict__ g, const float* __restrict__ bt,
                       int P, int tid){
  float* LNT = F + S_LNT; float* MR = F + S_MROW;
  for (int p = tid; p < P; p += TB) MR[p] = fdiv(np_sum(LNT + (p<<7), 128), 128.0f);
  __syncthreads();
  // squared deviations into scratch rows (reuse upper LNT? need separate) -> use HID head
  float* SQ = F + S_HID;   // safe: HID not live during LN
  for (int idx = tid; idx < P*128; idx += TB){
    int p = idx >> 7;
    float tv = fsub(LNT[idx], MR[p]);
    SQ[idx] = fmul(tv, tv);
  }
  __syncthreads();
  for (int p = tid; p < P; p += TB)
    MR[40+p] = sqrt_np(fadd(fdiv(np_sum(SQ + (p<<7), 128), 128.0f), 1e-5f));
  __syncthreads();
  for (int idx = tid; idx < P*128; idx += TB){
    int p = idx >> 7, o = idx & 127;
    float tv = fdiv(fsub(LNT[idx], MR[p]), MR[40+p]);
    out[idx] = fadd(fmul(tv, g[o]), bt[o]);
  }
  __syncthreads();
}

__device__ void prep_add(float* __restrict__ F, const float* __restrict__ A,
                         const float* __restrict__ Bv, int n, int tid){
  float* LNT = F + S_LNT;
  for (int idx = tid; idx < n; idx += TB) LNT[idx] = fadd(A[idx], Bv[idx]);
  __syncthreads();
}

// x = LN(x + FF(x)): ff1 relu (fmaf chain 128), ff2 (fmaf chain 2048), residual, LN
__device__ void ffn_run(float* __restrict__ F, float* __restrict__ xptr,
                        const float* __restrict__ W1, const float* __restrict__ b1,
                        const float* __restrict__ W2, const float* __restrict__ b2,
                        const float* __restrict__ g, const float* __restrict__ bt,
                        int P, int tid){
  float* HID = F + S_HID; float* Y = F + S_Y; float* LNT = F + S_LNT;
  for (int idx = tid; idx < P*2048; idx += TB){
    int p = idx >> 11, C = idx & 2047;
    const float* xr = xptr + (p<<7);
    const float* wr = W1 + C*128;
    float a = 0.f;
    for (int c = 0; c < 128; c++) a = fmaf(xr[c], wr[c], a);
    a = fadd(a, b1[C]);
    HID[idx] = fmaxf(a, 0.f);
  }
  __syncthreads();
  for (int idx = tid; idx < P*128; idx += TB){
    int p = idx >> 7, j = idx & 127;
    const float* hp = HID + (p<<11);
    const float* wp = W2 + j*2048;
    float a = 0.f;
    for (int C = 0; C < 2048; C++) a = fmaf(hp[C], wp[C], a);
    Y[idx] = fadd(a, b2[j]);
  }
  __syncthreads();
  for (int idx = tid; idx < P*128; idx += TB) LNT[idx] = fadd(xptr[idx], Y[idx]);
  __syncthreads();
  ln_run(F, xptr, g, bt, P, tid);
}

// pointer logits: QG = q@wq (fmaf chain); tarr[j]=v[j]*tanh(r+qg) unfused;
// LOG[k] = np_sum(tarr,128) - 1e7*mask[k] (unfused)
__device__ void ptr_run(float* __restrict__ F, const float* __restrict__ R,
                        const float* __restrict__ wq, const float* __restrict__ vv,
                        const float* __restrict__ qv, int tid){
  float* QG = F + S_QG; float* LOG = F + S_LOG; float* MASK = F + S_MASK;
  for (int j = tid; j < 128; j += TB){
    float a = 0.f;
    for (int c = 0; c < 128; c++) a = fmaf(qv[c], wq[c*128 + j], a);
    QG[j] = a;
  }
  __syncthreads();
  for (int k = tid; k < 32; k += TB){
    float tarr[128];
    const float* rr = R + (k<<7);
    for (int j = 0; j < 128; j++)
      tarr[j] = fmul(vv[j], tanh_np(fadd(rr[j], QG[j])));
    LOG[k] = fsub(np_sum(tarr, 128), fmul(10000000.0f, MASK[k]));
  }
  __syncthreads();
}

__global__ __launch_bounds__(TB) void k_main(Params pp){
  const int tid = threadIdx.x;
  float* __restrict__ F = pp.ws + (size_t)blockIdx.x * PB;
  for (int b = blockIdx.x; b < 64; b += pp.nb){
    // x_emb = x @ fc_w.T + fc_b (sgemm K=2 fused, bias after)
    for (int idx = tid; idx < 4096; idx += TB){
      int p = idx >> 7, o = idx & 127;
      float a = 0.f;
      a = fmaf(pp.x[(b*32+p)*2],   pp.fc_w[o*2],   a);
      a = fmaf(pp.x[(b*32+p)*2+1], pp.fc_w[o*2+1], a);
      F[S_XEMB + idx] = fadd(a, pp.fc_b[o]);
    }
    // PE (fp32 per reference; libm-grade sin/cos)
    for (int idx = tid; idx < 4224; idx += TB){
      int p = idx >> 7, o = idx & 127;
      int kk = o & ~1;
      float arg = fmul((float)(-9.210340371976184/128.0), (float)kk);
      float freq = exp_np(arg);
      float ang = fmul((float)p, freq);
      F[S_PE + idx] = (o & 1) ? cos_np(ang) : sin_np(ang);
    }
    for (int idx = tid; idx < 4224; idx += TB){
      int p = idx >> 7, o = idx & 127;
      F[S_TGT + idx] = (p == 0) ? pp.bos[o] : 0.f;
    }
    for (int k = tid; k < 32; k += TB) F[S_MASK + k] = 0.f;
    if (tid == 0){ F[S_LL] = 0.f; F[S_POS] = 0.f; }
    __syncthreads();

    // ---- encoder ----
    float* X = F + S_X;
    for (int idx = tid; idx < 4096; idx += TB) X[idx] = F[S_XEMB + idx];
    __syncthreads();
    for (int l = 0; l < 2; l++){
      qkv(F+S_Y, F+S_K, F+S_V, X, pp.eqkv_w + l*49152, pp.eqkv_b + l*384, 32, tid);
      __syncthreads();
      attn(F+S_ATT, F+S_Y, F+S_K, F+S_V, 32, 32, 32, tid);
      __syncthreads();
      gemv<false,true>(F+S_Y, F+S_ATT, pp.eout_w + l*16384, pp.eout_b + l*128, 128, 32, tid);
      __syncthreads();
      prep_add(F, X, F+S_Y, 4096, tid);
      ln_run(F, X, pp.eln1g + l*128, pp.eln1b + l*128, 32, tid);
      ffn_run(F, X, pp.eff1_w + l*262144, pp.eff1_b + l*2048,
              pp.eff2_w + l*262144, pp.eff2_b + l*128,
              pp.eln2g + l*128, pp.eln2b + l*128, 32, tid);
    }
    for (int idx = tid; idx < 4096; idx += TB) F[S_MEM + idx] = X[idx];
    __syncthreads();
    // cross K/V (bitwise step-invariant)
    for (int l = 0; l < 2; l++){
      qkv(F+S_Y, F+S_KC + l*8192, F+S_KC + l*8192 + 4096, F+S_MEM,
          pp.dcaqkv_w + l*49152, pp.dcaqkv_b + l*384, 32, tid);
      __syncthreads();
    }
    // r matrices: memory @ wref (fmaf chains, no bias)
    for (int idx = tid; idx < 4096; idx += TB){
      int k = idx >> 7, j = idx & 127;
      const float* mr = F + S_MEM + (k<<7);
      float a = 0.f, a2 = 0.f;
      for (int c = 0; c < 128; c++) a  = fmaf(mr[c], pp.wref_g[c*128 + j], a);
      for (int c = 0; c < 128; c++) a2 = fmaf(mr[c], pp.wref_a[c*128 + j], a2);
      F[S_RG + idx] = a;
      F[S_RA + idx] = a2;
    }
    __syncthreads();

    // ---- decode ----
    for (int i = 0; i < 32; i++){
      const int P = i + 1;
      // emb rows 0..i
      for (int idx = tid; idx < P*128; idx += TB){
        int p = idx >> 7, o = idx & 127;
        const float* tr = F + S_TGT + (p<<7);
        const float* wr = pp.demb_w + o*128;
        float a = 0.f;
        for (int c = 0; c < 128; c++) a = fmaf(tr[c], wr[c], a);
        a = fadd(a, pp.demb_b[o]);
        X[idx] = fadd(fmaxf(a, 0.f), F[S_PE + idx]);
      }
      __syncthreads();
      // decoder layer 1 (rows 0..i)
      qkv(F+S_Y, F+S_K, F+S_V, X, pp.dsaqkv_w, pp.dsaqkv_b, P, tid);
      __syncthreads();
      attn(F+S_ATT, F+S_Y, F+S_K, F+S_V, P, P, 33, tid);
      __syncthreads();
      gemv<false,true>(F+S_Y, F+S_ATT, pp.dsaout_w, pp.dsaout_b, 128, P, tid);
      __syncthreads();
      prep_add(F, X, F+S_Y, P*128, tid);
      ln_run(F, X, pp.dln1g, pp.dln1b, P, tid);
      gemv<false,true>(F+S_Y, X, pp.dcaqkv_w, pp.dcaqkv_b, 128, P, tid);
      __syncthreads();
      attn(F+S_ATT, F+S_Y, F+S_KC, F+S_KC+4096, P, 32, 32, tid);
      __syncthreads();
      gemv<false,true>(F+S_Y, F+S_ATT, pp.dcaout_w, pp.dcaout_b, 128, P, tid);
      __syncthreads();
      prep_add(F, X, F+S_Y, P*128, tid);
      ln_run(F, X, pp.dln2g, pp.dln2b, P, tid);
      ffn_run(F, X, pp.dff1_w, pp.dff1_b, pp.dff2_w, pp.dff2_b,
              pp.dln3g, pp.dln3b, P, tid);
      // decoder layer 2: K/V all P rows; query row i only
      qkv(F+S_Y, F+S_K, F+S_V, X, pp.dsaqkv_w + 49152, pp.dsaqkv_b + 384, P, tid);
      __syncthreads();
      attn(F+S_ATT, F+S_Y + ((P-1)<<7), F+S_K, F+S_V, 1, P, 33, tid);
      __syncthreads();
      gemv<false,true>(F+S_Y, F+S_ATT, pp.dsaout_w + 16384, pp.dsaout_b + 128, 128, 1, tid);
      __syncthreads();
      {
        float* LNT = F + S_LNT;
        for (int o = tid; o < 128; o += TB) LNT[o] = fadd(X[((P-1)<<7) + o], F[S_Y + o]);
        __syncthreads();
      }
      ln_run(F, F+S_VA, pp.dln1g + 128, pp.dln1b + 128, 1, tid);
      gemv<false,true>(F+S_VB, F+S_VA, pp.dcaqkv_w + 49152, pp.dcaqkv_b + 384, 128, 1, tid);
      __syncthreads();
      attn(F+S_ATT, F+S_VB, F+S_KC+8192, F+S_KC+12288, 1, 32, 32, tid);
      __syncthreads();
      gemv<false,true>(F+S_Y, F+S_ATT, pp.dcaout_w + 16384, pp.dcaout_b + 128, 128, 1, tid);
      __syncthreads();
      {
        float* LNT = F + S_LNT;
        for (int o = tid; o < 128; o += TB) LNT[o] = fadd(F[S_VA + o], F[S_Y + o]);
        __syncthreads();
      }
      ln_run(F, F+S_VA, pp.dln2g + 128, pp.dln2b + 128, 1, tid);
      ffn_run(F, F+S_VA, pp.dff1_w + 262144, pp.dff1_b + 2048,
              pp.dff2_w + 262144, pp.dff2_b + 128, pp.dln3g + 128, pp.dln3b + 128, 1, tid);
      // glimpse (NG=1)
      ptr_run(F, F+S_RG, pp.wq_g, pp.v_g, F+S_VA, tid);
      if (tid == 0){
        float* LOG = F + S_LOG; float* SOFT = F + S_SOFT;
        float m = LOG[0];
        for (int k = 1; k < 32; k++) m = fmaxf(m, LOG[k]);
        float e[32];
        for (int k = 0; k < 32; k++) e[k] = exp_np(fsub(LOG[k], m));
        float es = np_sum(e, 32);
        for (int k = 0; k < 32; k++) SOFT[k] = fdiv(e[k], es);
      }
      __syncthreads();
      // q' = einsum('bn,bnh->bh') — strided, scalar sequential, unfused
      for (int j = tid; j < 128; j += TB){
        float a = 0.f;
        for (int k = 0; k < 32; k++)
          a = fadd(a, fmul(F[S_SOFT + k], F[S_RG + (k<<7) + j]));
        F[S_VB + j] = a;
      }
      __syncthreads();
      // final pointer logits + selection via log_softmax values
      ptr_run(F, F+S_RA, pp.wq_a, pp.v_a, F+S_VB, tid);
      if (tid == 0){
        float* LOG = F + S_LOG; float* LP = F + S_LP;
        float m = LOG[0];
        for (int k = 1; k < 32; k++) m = fmaxf(m, LOG[k]);
        float e[32];
        for (int k = 0; k < 32; k++) e[k] = exp_np(fsub(LOG[k], m));
        float les = log_np(np_sum(e, 32));
        for (int k = 0; k < 32; k++) LP[k] = fsub(fsub(LOG[k], m), les);
        float best = LP[0]; int pos = 0;
        for (int k = 1; k < 32; k++){ if (LP[k] > best){ best = LP[k]; pos = k; } }
        F[S_LL] = fadd(F[S_LL], LP[pos]);
        F[S_MASK + pos] = 1.f;
        F[S_POS] = (float)pos;
        pp.out[b*32 + i] = (float)pos;
      }
      __syncthreads();
      {
        int pos = (int)F[S_POS];
        for (int o = tid; o < 128; o += TB)
          F[S_TGT + ((i+1)<<7) + o] = F[S_XEMB + (pos<<7) + o];
      }
      __syncthreads();
    }
    if (tid == 0) pp.out[2048 + b] = F[S_LL];
    __syncthreads();
  }
}

__global__ void k_signal(float* out, float val){
  int i = blockIdx.x*256 + threadIdx.x;
  if (i < 2112) out[i] = val;
}

extern "C" void kernel_launch(void* const* d_in, const int* in_sizes, int n_in,
                              void* d_out, int out_size, void* d_ws, size_t ws_size,
                              hipStream_t stream){
  const float* const* in = (const float* const*)d_in;
  float* out = (float*)d_out;
  size_t per = (size_t)PB * 4u;
  long long nb = (long long)(ws_size / per);
  if (nb < 1){
    k_signal<<<9, 256, 0, stream>>>(out, 100.0f + (float)(ws_size >> 20));
    return;
  }
  if (nb > 64) nb = 64;

  Params p;
  p.x=in[0]; p.fc_w=in[1]; p.fc_b=in[2]; p.bos=in[3];
  p.demb_w=in[4]; p.demb_b=in[5];
  p.eqkv_w=in[6]; p.eqkv_b=in[7]; p.eout_w=in[8]; p.eout_b=in[9];
  p.eff1_w=in[10]; p.eff1_b=in[11]; p.eff2_w=in[12]; p.eff2_b=in[13];
  p.eln1g=in[14]; p.eln1b=in[15]; p.eln2g=in[16]; p.eln2b=in[17];
  p.dsaqkv_w=in[18]; p.dsaqkv_b=in[19]; p.dsaout_w=in[20]; p.dsaout_b=in[21];
  p.dcaqkv_w=in[22]; p.dcaqkv_b=in[23]; p.dcaout_w=in[24]; p.dcaout_b=in[25];
  p.dff1_w=in[26]; p.dff1_b=in[27]; p.dff2_w=in[28]; p.dff2_b=in[29];
  p.dln1g=in[30]; p.dln1b=in[31]; p.dln2g=in[32]; p.dln2b=in[33]; p.dln3g=in[34]; p.dln3b=in[35];
  p.wref_g=in[36]; p.wq_g=in[37]; p.v_g=in[38]; p.wref_a=in[39]; p.wq_a=in[40]; p.v_a=in[41];
  p.ws = (float*)d_ws; p.out = out; p.nb = (int)nb;
  k_main<<<(int)nb, TB, 0, stream>>>(p);
}